// Round 9
// baseline (159.976 us; speedup 1.0000x reference)
//
#include <hip/hip_runtime.h>
#include <hip/hip_bf16.h>

#define N_NODES 50000
#define N_EDGES 800000
#define IN_FEAT 256
#define UNITS   128
#define DEGCAP  64          // per-node degree cap; Poisson(16) => P(>64) ~ 1e-20
#define BIN_SHIFT 6         // 64 tgts per bin
#define BIN_TGTS  64
#define NBINS   782         // ceil(50000 / 64)
#define BIN_CAP 1280        // Poisson(1023) + 8 sigma
#define CHUNK   4096        // edges per bin block
#define GEMM_BLOCKS 782     // (N_NODES+63)/64
#define BIN_BLOCKS  196     // ceil(N_EDGES/CHUNK)

typedef unsigned short ushort_t;
typedef __bf16 bf16x8 __attribute__((ext_vector_type(8)));
typedef float  f32x4  __attribute__((ext_vector_type(4)));
typedef unsigned short ushort8 __attribute__((ext_vector_type(8)));

// Hardware RNE f32->bf16 (compiler emits v_cvt_pk_bf16_f32 for pairs).
__device__ __forceinline__ ushort_t bfbits(float f) {
    __bf16 b = (__bf16)f;
    return __builtin_bit_cast(ushort_t, b);
}

__device__ __forceinline__ void cvt8(const float4& f0, const float4& f1,
                                     ushort_t* dst) {
    bf16x8 u;
    u[0] = (__bf16)f0.x; u[1] = (__bf16)f0.y; u[2] = (__bf16)f0.z; u[3] = (__bf16)f0.w;
    u[4] = (__bf16)f1.x; u[5] = (__bf16)f1.y; u[6] = (__bf16)f1.z; u[7] = (__bf16)f1.w;
    *(bf16x8*)dst = u;
}

// ---------------------------------------------------------------------------
// K0: Wt[n][k] = bf16(W[k][n])  (128 x 256 bf16, 64 KB) + zero gbin[0..1023].
// ---------------------------------------------------------------------------
__global__ __launch_bounds__(256) void prep_wt_zero(const float* __restrict__ W,
                                                    ushort_t* __restrict__ Wt,
                                                    int* __restrict__ gbin) {
    int i = blockIdx.x * 256 + threadIdx.x;
    if (i < UNITS * IN_FEAT) {
        int n = i >> 8;
        int k = i & 255;
        Wt[i] = bfbits(W[(size_t)k * UNITS + n]);
    }
    if (i < 1024) gbin[i] = 0;
}

__device__ __forceinline__ float edge_score(float at, float as) {
    float s = at + as;
    s = s > 0.f ? s : 0.2f * s;          // leaky_relu
    s = fminf(fmaxf(s, -2.f), 2.f);      // clip
    return __expf(s);
}

// ---------------------------------------------------------------------------
// K1: grid-fused GEMM + edge-binning. Blocks [0,782) do the MFMA gemm
// (identical structure to R8's gemm_mfma); blocks [782,978) run the radix
// bin pass at 256 threads. Disjoint inputs -> bin work fills the gemm
// tail + removes one launch gap. LDS is a 78.8 KB union.
// NOTE: Wt must NOT alias binbuf (gemm reads Wt while bin writes binbuf).
// ---------------------------------------------------------------------------
__global__ __launch_bounds__(256) void gemm_bin(
        const float* __restrict__ A, const ushort_t* __restrict__ Wt,
        const float* __restrict__ ka, const int* __restrict__ edges,
        int* __restrict__ gbin, int2* __restrict__ binbuf,
        ushort_t* __restrict__ Hb, float* __restrict__ a_tgt,
        float* __restrict__ a_src, int M, int E) {
    __shared__ __align__(16) char smem[78848];
    const int tid  = threadIdx.x;
    const int lane = tid & 63;
    const int wv   = tid >> 6;

    if (blockIdx.x < GEMM_BLOCKS) {
        // ================= GEMM branch =================
        ushort_t* Bs = (ushort_t*)smem;                // 128*264*2 = 67584 B
        ushort_t* As = Bs + 128 * 264;                 // 2*64*40*2 = 10240 B
        float (*spt)[2] = (float(*)[2])(As + 2 * 64 * 40);  // 512 B
        float (*sps)[2] = spt + 64;                    // 512 B
        const int wy   = wv >> 1;
        const int wx   = wv & 1;
        const int row0 = blockIdx.x * 64;
        const int quad = lane >> 4;
        const int cl   = lane & 15;

        f32x4 acc[2][4] = {};

        // stage B once: Wt[128][256] -> Bs[128][264]
#pragma unroll
        for (int t = 0; t < 16; ++t) {
            int j = t * 256 + tid;
            int r = j >> 5;
            int c = (j & 31) * 8;
            *(ushort8*)(Bs + r * 264 + c) = *(const ushort8*)(Wt + r * 256 + c);
        }

        const int ar = tid >> 2, aq = tid & 3;
        const int gr = min(row0 + ar, M - 1);
        const float* aptr = A + (size_t)gr * IN_FEAT + aq * 8;
        ushort_t*    asw  = As + ar * 40 + aq * 8;

        {   // prologue: tile kc=0 into buf0
            float4 f0 = *(const float4*)(aptr);
            float4 f1 = *(const float4*)(aptr + 4);
            cvt8(f0, f1, asw);
        }
        __syncthreads();

        for (int kc = 0; kc < IN_FEAT; kc += 32) {
            const int cur = (kc >> 5) & 1;
            const bool more = (kc + 32 < IN_FEAT);
            float4 g0, g1;
            if (more) {
                g0 = *(const float4*)(aptr + kc + 32);
                g1 = *(const float4*)(aptr + kc + 36);
            }

            bf16x8 af[2], bff[4];
            const ushort_t* asb = As + cur * 2560;
#pragma unroll
            for (int mi = 0; mi < 2; ++mi)
                af[mi] = *(const bf16x8*)(asb + (wy * 32 + mi * 16 + cl) * 40 + quad * 8);
#pragma unroll
            for (int ni = 0; ni < 4; ++ni)
                bff[ni] = *(const bf16x8*)(Bs + (wx * 64 + ni * 16 + cl) * 264 + kc + quad * 8);
#pragma unroll
            for (int mi = 0; mi < 2; ++mi)
#pragma unroll
                for (int ni = 0; ni < 4; ++ni)
                    acc[mi][ni] = __builtin_amdgcn_mfma_f32_16x16x32_bf16(
                        af[mi], bff[ni], acc[mi][ni], 0, 0, 0);

            if (more)
                cvt8(g0, g1, As + (cur ^ 1) * 2560 + ar * 40 + aq * 8);
            __syncthreads();
        }

        // Hb store (bf16)
#pragma unroll
        for (int mi = 0; mi < 2; ++mi) {
#pragma unroll
            for (int ni = 0; ni < 4; ++ni) {
                int col = wx * 64 + ni * 16 + cl;
#pragma unroll
                for (int r = 0; r < 4; ++r) {
                    int row = row0 + wy * 32 + mi * 16 + quad * 4 + r;
                    if (row < M)
                        Hb[(size_t)row * UNITS + col] = bfbits(acc[mi][ni][r]);
                }
            }
        }

        // fused attention logits
        float kt[4], ks[4];
#pragma unroll
        for (int ni = 0; ni < 4; ++ni) {
            int col = wx * 64 + ni * 16 + cl;
            kt[ni] = ka[col];
            ks[ni] = ka[UNITS + col];
        }
#pragma unroll
        for (int mi = 0; mi < 2; ++mi) {
            float pt[4] = {}, ps[4] = {};
#pragma unroll
            for (int ni = 0; ni < 4; ++ni)
#pragma unroll
                for (int r = 0; r < 4; ++r) {
                    pt[r] += acc[mi][ni][r] * kt[ni];
                    ps[r] += acc[mi][ni][r] * ks[ni];
                }
#pragma unroll
            for (int r = 0; r < 4; ++r) {
#pragma unroll
                for (int m = 1; m < 16; m <<= 1) {
                    pt[r] += __shfl_xor(pt[r], m);
                    ps[r] += __shfl_xor(ps[r], m);
                }
                if (cl == 0) {
                    int rl = wy * 32 + mi * 16 + quad * 4 + r;
                    spt[rl][wx] = pt[r];
                    sps[rl][wx] = ps[r];
                }
            }
        }
        __syncthreads();
        if (tid < 64) {
            int row = row0 + tid;
            if (row < M) {
                a_tgt[row] = spt[tid][0] + spt[tid][1];
                a_src[row] = sps[tid][0] + sps[tid][1];
            }
        }
    } else {
        // ================= BIN branch (256 threads) =================
        int*  hist   = (int*)smem;                     // 1024 ints
        int*  sbase  = hist + 1024;
        int*  runoff = sbase + 1024;
        int*  gbase  = runoff + 1024;
        int*  wsum4  = gbase + 1024;                   // 4 ints (+pad)
        int2* stage  = (int2*)(smem + 16400);          // 4096 int2 = 32768 B
        const int e0 = (blockIdx.x - GEMM_BLOCKS) * CHUNK;

#pragma unroll
        for (int j = 0; j < 4; ++j) hist[j * 256 + tid] = 0;
        __syncthreads();

        int2 er[16];
        int  eb[16];
#pragma unroll
        for (int j = 0; j < 16; ++j) {
            int idx = e0 + j * 256 + tid;              // coalesced
            if (idx < E) {
                er[j] = ((const int2*)edges)[idx];
                eb[j] = er[j].x >> BIN_SHIFT;
                atomicAdd(&hist[eb[j]], 1);
            } else eb[j] = -1;
        }
        __syncthreads();

        // scan 1024 hist entries with 256 threads (4 serial each)
        int h[4];
        int s = 0;
#pragma unroll
        for (int i = 0; i < 4; ++i) { h[i] = hist[4 * tid + i]; s += h[i]; }
        int incl = s;
#pragma unroll
        for (int off = 1; off < 64; off <<= 1) {
            int t = __shfl_up(incl, off);
            if (lane >= off) incl += t;
        }
        if (lane == 63) wsum4[wv] = incl;
        __syncthreads();
        int excl = incl - s;
#pragma unroll
        for (int w = 0; w < 4; ++w) if (w < wv) excl += wsum4[w];
        {
            int r = excl;
#pragma unroll
            for (int i = 0; i < 4; ++i) {
                sbase[4 * tid + i]  = r;
                runoff[4 * tid + i] = r;
                r += h[i];
            }
        }
        __syncthreads();                               // runoff/sbase visible

        // reserve global per-bin space (one atomic per non-empty (block,bin))
#pragma unroll
        for (int i = 0; i < 4; ++i) {
            int b = 4 * tid + i;
            if (h[i] > 0) gbase[b] = atomicAdd(&gbin[b], h[i]);
        }

        // bin-sorted staging
#pragma unroll
        for (int j = 0; j < 16; ++j) {
            if (eb[j] >= 0) {
                int p = atomicAdd(&runoff[eb[j]], 1);
                stage[p] = er[j];
            }
        }
        __syncthreads();                               // stage + gbase done

        int total = min(CHUNK, E - e0);
        for (int p = tid; p < total; p += 256) {       // coalesced run writes
            int2 ts = stage[p];
            int b   = ts.x >> BIN_SHIFT;
            int dst = gbase[b] + (p - sbase[b]);
            if (dst < BIN_CAP)
                binbuf[(size_t)b * BIN_CAP + dst] = ts;
        }
    }
}

// ---------------------------------------------------------------------------
// K2: fused scatter+aggregate, one block (512 thr = 8 waves) per bin of
// 64 targets, compact LDS CSR (~11.5 KB).
// Phase-2 v3: 2 nodes in flight + 2-DEEP SOFTWARE PREFETCH -- iteration
// t+1's lcsr+Hb loads are issued before consuming iteration t, so the
// waitcnt before t's FMAs leaves t+1's loads in flight (4 outstanding
// gathers/wave instead of 2). Guarded slots read Hb row 0 with w=0.
// ---------------------------------------------------------------------------
__global__ __launch_bounds__(512) void scatter_aggregate(
        const int2* __restrict__ binbuf, const int* __restrict__ gbin,
        const float* __restrict__ at, const float* __restrict__ as,
        const ushort_t* __restrict__ Hb, float* __restrict__ out, int M) {
    __shared__ int2  lcsr[BIN_CAP];             // 10.2 KB compact CSR
    __shared__ int   lcnt[BIN_TGTS];
    __shared__ int   loff[BIN_TGTS];
    __shared__ int   roff[BIN_TGTS];
    __shared__ float atl[BIN_TGTS];
    const int tid = threadIdx.x;
    const int bin = blockIdx.x;
    const int t0  = bin << BIN_SHIFT;
    if (tid < BIN_TGTS) {
        lcnt[tid] = 0;
        int t = t0 + tid;
        atl[tid] = (t < M) ? at[t] : 0.f;
    }
    __syncthreads();

    const int bcnt = min(gbin[bin], BIN_CAP);
    const int2* src = binbuf + (size_t)bin * BIN_CAP;

    // ---- pass A: histogram ----
    for (int p = tid; p < bcnt; p += 512) {
        int2 ts = src[p];                       // coalesced, L2-hot
        atomicAdd(&lcnt[ts.x - t0], 1);
    }
    __syncthreads();

    // ---- scan lcnt[0..63] -> exclusive offsets (single wave) ----
    if (tid < 64) {
        int h = lcnt[tid];
        int incl = h;
#pragma unroll
        for (int off = 1; off < 64; off <<= 1) {
            int t = __shfl_up(incl, off);
            if (tid >= off) incl += t;
        }
        loff[tid] = incl - h;
        roff[tid] = incl - h;
    }
    __syncthreads();

    // ---- pass B: score + place into compact CSR ----
    for (int p = tid; p < bcnt; p += 512) {
        int2 ts = src[p];
        int lt  = ts.x - t0;
        float sc = edge_score(atl[lt], as[ts.y]);
        int r = atomicAdd(&roff[lt], 1);        // LDS atomic
        lcsr[r] = make_int2(ts.y, __float_as_int(sc));
    }
    __syncthreads();

    // ---- phase 2: 2 nodes x 2-deep prefetch ----
    const int lane = tid & 63;
    const int wv   = tid >> 6;                  // 0..7
    const int g    = lane >> 4;                 // edge slot 0..3
    const int c    = lane & 15;                 // feature chunk [c*8, c*8+8)

#pragma unroll
    for (int ln = 0; ln < 8; ln += 2) {
        const int ltA = wv * 8 + ln;
        const int ltB = ltA + 1;
        const int begA = loff[ltA], degA = min(lcnt[ltA], DEGCAP);
        const int begB = loff[ltB], degB = min(lcnt[ltB], DEGCAP);

        float accA[8] = {}, accB[8] = {};
        float wsA = 0.f, wsB = 0.f;
        const int ns = (max(degA, degB) + 3) >> 2;

        // issue iteration 0
        int2 cA = (g < degA) ? lcsr[begA + g] : make_int2(0, 0);
        int2 cB = (g < degB) ? lcsr[begB + g] : make_int2(0, 0);
        uint4 cuA = *(const uint4*)(Hb + (size_t)cA.x * UNITS + c * 8);
        uint4 cuB = *(const uint4*)(Hb + (size_t)cB.x * UNITS + c * 8);

        for (int t = 0; t < ns; ++t) {
            // issue iteration t+1 (stays in flight across t's consume)
            const int sl1 = (t + 1) * 4 + g;
            int2 nA = (t + 1 < ns && sl1 < degA) ? lcsr[begA + sl1] : make_int2(0, 0);
            int2 nB = (t + 1 < ns && sl1 < degB) ? lcsr[begB + sl1] : make_int2(0, 0);
            uint4 nuA = *(const uint4*)(Hb + (size_t)nA.x * UNITS + c * 8);
            uint4 nuB = *(const uint4*)(Hb + (size_t)nB.x * UNITS + c * 8);

            // consume iteration t
            const float wA = __int_as_float(cA.y);
            const float wB = __int_as_float(cB.y);
            wsA += wA; wsB += wB;
            accA[0] += wA * __uint_as_float(cuA.x << 16);
            accA[1] += wA * __uint_as_float(cuA.x & 0xffff0000u);
            accA[2] += wA * __uint_as_float(cuA.y << 16);
            accA[3] += wA * __uint_as_float(cuA.y & 0xffff0000u);
            accA[4] += wA * __uint_as_float(cuA.z << 16);
            accA[5] += wA * __uint_as_float(cuA.z & 0xffff0000u);
            accA[6] += wA * __uint_as_float(cuA.w << 16);
            accA[7] += wA * __uint_as_float(cuA.w & 0xffff0000u);
            accB[0] += wB * __uint_as_float(cuB.x << 16);
            accB[1] += wB * __uint_as_float(cuB.x & 0xffff0000u);
            accB[2] += wB * __uint_as_float(cuB.y << 16);
            accB[3] += wB * __uint_as_float(cuB.y & 0xffff0000u);
            accB[4] += wB * __uint_as_float(cuB.z << 16);
            accB[5] += wB * __uint_as_float(cuB.z & 0xffff0000u);
            accB[6] += wB * __uint_as_float(cuB.w << 16);
            accB[7] += wB * __uint_as_float(cuB.w & 0xffff0000u);

            cA = nA; cB = nB; cuA = nuA; cuB = nuB;
        }

        // combine the 4 edge-slot partials; same tree finishes denominators
#pragma unroll
        for (int i = 0; i < 8; ++i) {
            accA[i] += __shfl_xor(accA[i], 16);
            accA[i] += __shfl_xor(accA[i], 32);
            accB[i] += __shfl_xor(accB[i], 16);
            accB[i] += __shfl_xor(accB[i], 32);
        }
        wsA += __shfl_xor(wsA, 16); wsA += __shfl_xor(wsA, 32);
        wsB += __shfl_xor(wsB, 16); wsB += __shfl_xor(wsB, 32);
        const float scA = (degA > 0) ? 1.0f / wsA : 0.0f;
        const float scB = (degB > 0) ? 1.0f / wsB : 0.0f;

        if (g == 0) {                           // 16 lanes x 32B contiguous
            const int nodeA = t0 + ltA;
            const int nodeB = t0 + ltB;
            if (nodeA < M) {
                float* dst = out + (size_t)nodeA * UNITS + c * 8;
                *(float4*)dst       = make_float4(accA[0] * scA, accA[1] * scA,
                                                  accA[2] * scA, accA[3] * scA);
                *(float4*)(dst + 4) = make_float4(accA[4] * scA, accA[5] * scA,
                                                  accA[6] * scA, accA[7] * scA);
            }
            if (nodeB < M) {
                float* dst = out + (size_t)nodeB * UNITS + c * 8;
                *(float4*)dst       = make_float4(accB[0] * scB, accB[1] * scB,
                                                  accB[2] * scB, accB[3] * scB);
                *(float4*)(dst + 4) = make_float4(accB[4] * scB, accB[5] * scB,
                                                  accB[6] * scB, accB[7] * scB);
            }
        }
    }
}

// ---------------------------------------------------------------------------
extern "C" void kernel_launch(void* const* d_in, const int* in_sizes, int n_in,
                              void* d_out, int out_size, void* d_ws, size_t ws_size,
                              hipStream_t stream) {
    const float* node_states = (const float*)d_in[0];
    const int*   edges       = (const int*)d_in[1];   // int32 pairs (tgt,src)
    const float* W           = (const float*)d_in[2];
    const float* ka          = (const float*)d_in[3];
    float*       out         = (float*)d_out;

    const int M = N_NODES, E = N_EDGES;

    // workspace layout -- NOTE: wt no longer aliases binbuf (gemm reads Wt
    // while bin blocks of the SAME kernel write binbuf).
    ushort_t* hb     = (ushort_t*)d_ws;                  // M*128 bf16 = 12.8 MB
    float*    a_tgt  = (float*)(hb + (size_t)M * UNITS); // M floats
    float*    a_src  = a_tgt + M;                        // M floats
    int*      gbin   = (int*)(a_src + M);                // 1024 ints (zeroed by K0)
    int2*     binbuf = (int2*)(gbin + 1024);             // NBINS*BIN_CAP int2 = 8.0 MB
    ushort_t* wt     = (ushort_t*)(binbuf + (size_t)NBINS * BIN_CAP); // 64 KB

    prep_wt_zero    <<<(UNITS * IN_FEAT + 255) / 256, 256, 0, stream>>>(W, wt, gbin);
    gemm_bin        <<<GEMM_BLOCKS + BIN_BLOCKS, 256, 0, stream>>>(
                        node_states, wt, ka, edges, gbin, binbuf,
                        hb, a_tgt, a_src, M, E);
    scatter_aggregate<<<NBINS, 512, 0, stream>>>(binbuf, gbin, a_tgt, a_src,
                                                 hb, out, M);
}

// Round 10
// 156.388 us; speedup vs baseline: 1.0229x; 1.0229x over previous
//
#include <hip/hip_runtime.h>
#include <hip/hip_bf16.h>

#define N_NODES 50000
#define N_EDGES 800000
#define IN_FEAT 256
#define UNITS   128
#define DEGCAP  64          // per-node degree cap; Poisson(16) => P(>64) ~ 1e-20
#define BIN_SHIFT 6         // 64 tgts per bin
#define BIN_TGTS  64
#define NBINS   782         // ceil(50000 / 64)
#define BIN_CAP 1280        // Poisson(1023) + 8 sigma
#define CHUNK   4096        // edges per bin_edges block
#define GPAD    16          // gbin padding: 1 counter per 64B line

typedef unsigned short ushort_t;
typedef __bf16 bf16x8 __attribute__((ext_vector_type(8)));
typedef float  f32x4  __attribute__((ext_vector_type(4)));
typedef unsigned short ushort8 __attribute__((ext_vector_type(8)));

// Hardware RNE f32->bf16 (compiler emits v_cvt_pk_bf16_f32 for pairs).
__device__ __forceinline__ ushort_t bfbits(float f) {
    __bf16 b = (__bf16)f;
    return __builtin_bit_cast(ushort_t, b);
}

__device__ __forceinline__ void cvt8(const float4& f0, const float4& f1,
                                     ushort_t* dst) {
    bf16x8 u;
    u[0] = (__bf16)f0.x; u[1] = (__bf16)f0.y; u[2] = (__bf16)f0.z; u[3] = (__bf16)f0.w;
    u[4] = (__bf16)f1.x; u[5] = (__bf16)f1.y; u[6] = (__bf16)f1.z; u[7] = (__bf16)f1.w;
    *(bf16x8*)dst = u;
}

// ---------------------------------------------------------------------------
// K0: Wt[n][k] = bf16(W[k][n])  (128 x 256 bf16, 64 KB) + zero padded gbin
// (1024*GPAD ints = 64 KB -- one counter per cache line).
// ---------------------------------------------------------------------------
__global__ __launch_bounds__(256) void prep_wt_zero(const float* __restrict__ W,
                                                    ushort_t* __restrict__ Wt,
                                                    int* __restrict__ gbin) {
    int i = blockIdx.x * 256 + threadIdx.x;
    if (i < UNITS * IN_FEAT) {
        int n = i >> 8;
        int k = i & 255;
        Wt[i] = bfbits(W[(size_t)k * UNITS + n]);
    }
    if (i < 1024 * GPAD) gbin[i] = 0;
}

__device__ __forceinline__ float edge_score(float at, float as) {
    float s = at + as;
    s = s > 0.f ? s : 0.2f * s;          // leaky_relu
    s = fminf(fmaxf(s, -2.f), 2.f);      // clip
    return __expf(s);
}

// ---------------------------------------------------------------------------
// K1: h(bf16) = A @ W via MFMA 16x16x32 bf16. BM=64, BN=128, 4 waves 2x2.
// v3 (this round): DEPTH-3 REGISTER PREFETCH on the A staging. The poison
// fills flush L3 between iterations, so A loads are ~900cy HBM misses;
// with the old 1-step double-buffer every K-step exposed nearly a full
// miss (measured: MfmaUtil 2.4%, VALUBusy 6%). Now step s issues the
// load for s+3; the LDS write of s+1's data uses a value issued ~2.5
// step-times earlier. Fully unrolled -> slot index s%3 is compile-time.
// Fused epilogue: attention logits from the f32 accumulators.
// ---------------------------------------------------------------------------
__global__ __launch_bounds__(256) void gemm_mfma(const float* __restrict__ A,
                                                 const ushort_t* __restrict__ Wt,
                                                 const float* __restrict__ ka,
                                                 ushort_t* __restrict__ Hb,
                                                 float* __restrict__ a_tgt,
                                                 float* __restrict__ a_src, int M) {
    __shared__ __align__(16) ushort_t Bs[128 * 264];   // 67.6 KB, staged once
    __shared__ __align__(16) ushort_t As[2 * 64 * 40]; // 10.2 KB double buffer
    __shared__ float spt[64][2];
    __shared__ float sps[64][2];
    const int tid  = threadIdx.x;
    const int lane = tid & 63;
    const int wv   = tid >> 6;
    const int wy   = wv >> 1;
    const int wx   = wv & 1;
    const int row0 = blockIdx.x * 64;
    const int quad = lane >> 4;
    const int cl   = lane & 15;

    f32x4 acc[2][4] = {};

    // ---- stage B once: Wt[128][256] -> Bs[128][264] ----
#pragma unroll
    for (int t = 0; t < 16; ++t) {
        int j = t * 256 + tid;
        int r = j >> 5;
        int c = (j & 31) * 8;
        *(ushort8*)(Bs + r * 264 + c) = *(const ushort8*)(Wt + r * 256 + c);
    }

    // ---- A staging setup ----
    const int ar = tid >> 2, aq = tid & 3;
    const int gr = min(row0 + ar, M - 1);
    const float* aptr = A + (size_t)gr * IN_FEAT + aq * 8;
    ushort_t* aw0 = As + ar * 40 + aq * 8;
    ushort_t* aw1 = As + 2560 + ar * 40 + aq * 8;

    // prologue: issue loads for steps 0,1,2; write step 0 into buf0
    float4 pa[3], pb[3];
    pa[0] = *(const float4*)(aptr);       pb[0] = *(const float4*)(aptr + 4);
    pa[1] = *(const float4*)(aptr + 32);  pb[1] = *(const float4*)(aptr + 36);
    pa[2] = *(const float4*)(aptr + 64);  pb[2] = *(const float4*)(aptr + 68);
    cvt8(pa[0], pb[0], aw0);
    __syncthreads();                                  // B + A(buf0) visible

#pragma unroll
    for (int s = 0; s < 8; ++s) {
        const int kc = s * 32;
        // (1) issue load for step s+3 into the slot freed at step s
        if (s + 3 < 8) {
            pa[s % 3] = *(const float4*)(aptr + kc + 96);
            pb[s % 3] = *(const float4*)(aptr + kc + 100);
        }

        // (2) ds_read fragments + MFMA on buffer s&1
        bf16x8 af[2], bff[4];
        const ushort_t* asb = As + (s & 1) * 2560;
#pragma unroll
        for (int mi = 0; mi < 2; ++mi)
            af[mi] = *(const bf16x8*)(asb + (wy * 32 + mi * 16 + cl) * 40 + quad * 8);
#pragma unroll
        for (int ni = 0; ni < 4; ++ni)
            bff[ni] = *(const bf16x8*)(Bs + (wx * 64 + ni * 16 + cl) * 264 + kc + quad * 8);
#pragma unroll
        for (int mi = 0; mi < 2; ++mi)
#pragma unroll
            for (int ni = 0; ni < 4; ++ni)
                acc[mi][ni] = __builtin_amdgcn_mfma_f32_16x16x32_bf16(
                    af[mi], bff[ni], acc[mi][ni], 0, 0, 0);

        // (3) write step s+1's data (issued at step s-2) into the other buf
        if (s + 1 < 8)
            cvt8(pa[(s + 1) % 3], pb[(s + 1) % 3], (s & 1) ? aw0 : aw1);
        __syncthreads();
    }

    // ---- Hb store (bf16) ----
#pragma unroll
    for (int mi = 0; mi < 2; ++mi) {
#pragma unroll
        for (int ni = 0; ni < 4; ++ni) {
            int col = wx * 64 + ni * 16 + cl;
#pragma unroll
            for (int r = 0; r < 4; ++r) {
                int row = row0 + wy * 32 + mi * 16 + quad * 4 + r;
                if (row < M)
                    Hb[(size_t)row * UNITS + col] = bfbits(acc[mi][ni][r]);
            }
        }
    }

    // ---- fused attention logits: a_tgt/a_src = acc . ka ----
    float kt[4], ks[4];
#pragma unroll
    for (int ni = 0; ni < 4; ++ni) {
        int col = wx * 64 + ni * 16 + cl;
        kt[ni] = ka[col];
        ks[ni] = ka[UNITS + col];
    }
#pragma unroll
    for (int mi = 0; mi < 2; ++mi) {
        float pt[4] = {}, ps[4] = {};
#pragma unroll
        for (int ni = 0; ni < 4; ++ni)
#pragma unroll
            for (int r = 0; r < 4; ++r) {
                pt[r] += acc[mi][ni][r] * kt[ni];
                ps[r] += acc[mi][ni][r] * ks[ni];
            }
#pragma unroll
        for (int r = 0; r < 4; ++r) {
#pragma unroll
            for (int m = 1; m < 16; m <<= 1) {
                pt[r] += __shfl_xor(pt[r], m);
                ps[r] += __shfl_xor(ps[r], m);
            }
            if (cl == 0) {
                int rl = wy * 32 + mi * 16 + quad * 4 + r;
                spt[rl][wx] = pt[r];
                sps[rl][wx] = ps[r];
            }
        }
    }
    __syncthreads();
    if (tid < 64) {
        int row = row0 + tid;
        if (row < M) {
            a_tgt[row] = spt[tid][0] + spt[tid][1];
            a_src[row] = sps[tid][0] + sps[tid][1];
        }
    }
}

// ---------------------------------------------------------------------------
// K2: radix bin pass, 1024 threads (R8 structure). The per-(block,bin)
// reservation atomic now hits a PADDED counter array (gbin[b*GPAD]) --
// ~150K atomics spread over 782 cache lines instead of 12.
// ---------------------------------------------------------------------------
__global__ __launch_bounds__(1024) void bin_edges(const int* __restrict__ edges,
                                                  int* __restrict__ gbin,
                                                  int2* __restrict__ binbuf, int E) {
    __shared__ int  hist[1024];
    __shared__ int  sbase[1024];
    __shared__ int  runoff[1024];
    __shared__ int  gbase[1024];
    __shared__ int  wsum[16];
    __shared__ int2 stage[CHUNK];   // 32 KB
    const int tid  = threadIdx.x;
    const int lane = tid & 63, wv = tid >> 6;
    const int e0   = blockIdx.x * CHUNK;

    hist[tid] = 0;
    __syncthreads();

    int2 er[4];
    int  eb[4];
#pragma unroll
    for (int j = 0; j < 4; ++j) {
        int idx = e0 + j * 1024 + tid;          // coalesced
        if (idx < E) {
            er[j] = ((const int2*)edges)[idx];
            eb[j] = er[j].x >> BIN_SHIFT;
            atomicAdd(&hist[eb[j]], 1);
        } else eb[j] = -1;
    }
    __syncthreads();

    // exclusive scan of hist[0..1023]
    int h = hist[tid];
    int incl = h;
#pragma unroll
    for (int off = 1; off < 64; off <<= 1) {
        int t = __shfl_up(incl, off);
        if (lane >= off) incl += t;
    }
    if (lane == 63) wsum[wv] = incl;
    __syncthreads();
    int excl = incl - h;
#pragma unroll
    for (int w = 0; w < 16; ++w) if (w < wv) excl += wsum[w];
    sbase[tid]  = excl;
    runoff[tid] = excl;
    __syncthreads();

    if (h > 0) gbase[tid] = atomicAdd(&gbin[tid * GPAD], h);  // padded!

#pragma unroll
    for (int j = 0; j < 4; ++j) {
        if (eb[j] >= 0) {
            int p = atomicAdd(&runoff[eb[j]], 1);
            stage[p] = er[j];
        }
    }
    __syncthreads();

    int total = sbase[1023] + hist[1023];
    for (int p = tid; p < total; p += 1024) {   // coalesced run writes
        int2 ts = stage[p];
        int b   = ts.x >> BIN_SHIFT;
        int dst = gbase[b] + (p - sbase[b]);
        if (dst < BIN_CAP)
            binbuf[(size_t)b * BIN_CAP + dst] = ts;
    }
}

// ---------------------------------------------------------------------------
// K3: fused scatter+aggregate (R8 structure), one block (512 thr) per bin
// of 64 targets, compact LDS CSR. Only change: padded gbin read.
// ---------------------------------------------------------------------------
__global__ __launch_bounds__(512) void scatter_aggregate(
        const int2* __restrict__ binbuf, const int* __restrict__ gbin,
        const float* __restrict__ at, const float* __restrict__ as,
        const ushort_t* __restrict__ Hb, float* __restrict__ out, int M) {
    __shared__ int2  lcsr[BIN_CAP];             // 10.2 KB compact CSR
    __shared__ int   lcnt[BIN_TGTS];
    __shared__ int   loff[BIN_TGTS];
    __shared__ int   roff[BIN_TGTS];
    __shared__ float atl[BIN_TGTS];
    const int tid = threadIdx.x;
    const int bin = blockIdx.x;
    const int t0  = bin << BIN_SHIFT;
    if (tid < BIN_TGTS) {
        lcnt[tid] = 0;
        int t = t0 + tid;
        atl[tid] = (t < M) ? at[t] : 0.f;
    }
    __syncthreads();

    const int bcnt = min(gbin[bin * GPAD], BIN_CAP);
    const int2* src = binbuf + (size_t)bin * BIN_CAP;

    // ---- pass A: histogram ----
    for (int p = tid; p < bcnt; p += 512) {
        int2 ts = src[p];
        atomicAdd(&lcnt[ts.x - t0], 1);
    }
    __syncthreads();

    // ---- scan lcnt[0..63] -> exclusive offsets (single wave) ----
    if (tid < 64) {
        int h = lcnt[tid];
        int incl = h;
#pragma unroll
        for (int off = 1; off < 64; off <<= 1) {
            int t = __shfl_up(incl, off);
            if (tid >= off) incl += t;
        }
        loff[tid] = incl - h;
        roff[tid] = incl - h;
    }
    __syncthreads();

    // ---- pass B: score + place into compact CSR ----
    for (int p = tid; p < bcnt; p += 512) {
        int2 ts = src[p];
        int lt  = ts.x - t0;
        float sc = edge_score(atl[lt], as[ts.y]);
        int r = atomicAdd(&roff[lt], 1);
        lcsr[r] = make_int2(ts.y, __float_as_int(sc));
    }
    __syncthreads();

    // ---- phase 2: aggregate, 2 nodes in flight per wave iteration ----
    const int lane = tid & 63;
    const int wv   = tid >> 6;
    const int g    = lane >> 4;
    const int c    = lane & 15;

#pragma unroll
    for (int ln = 0; ln < 8; ln += 2) {
        const int ltA = wv * 8 + ln;
        const int ltB = ltA + 1;
        const int begA = loff[ltA], degA = min(lcnt[ltA], DEGCAP);
        const int begB = loff[ltB], degB = min(lcnt[ltB], DEGCAP);

        float accA[8] = {}, accB[8] = {};
        float wsA = 0.f, wsB = 0.f;
        const int ns = (max(degA, degB) + 3) >> 2;
        for (int t = 0; t < ns; ++t) {
            const int slot = t * 4 + g;
            int2 swA = (slot < degA) ? lcsr[begA + slot] : make_int2(0, 0);
            int2 swB = (slot < degB) ? lcsr[begB + slot] : make_int2(0, 0);
            float wA = __int_as_float(swA.y);
            float wB = __int_as_float(swB.y);
            uint4 uA = *(const uint4*)(Hb + (size_t)swA.x * UNITS + c * 8);
            uint4 uB = *(const uint4*)(Hb + (size_t)swB.x * UNITS + c * 8);
            wsA += wA; wsB += wB;
            accA[0] += wA * __uint_as_float(uA.x << 16);
            accA[1] += wA * __uint_as_float(uA.x & 0xffff0000u);
            accA[2] += wA * __uint_as_float(uA.y << 16);
            accA[3] += wA * __uint_as_float(uA.y & 0xffff0000u);
            accA[4] += wA * __uint_as_float(uA.z << 16);
            accA[5] += wA * __uint_as_float(uA.z & 0xffff0000u);
            accA[6] += wA * __uint_as_float(uA.w << 16);
            accA[7] += wA * __uint_as_float(uA.w & 0xffff0000u);
            accB[0] += wB * __uint_as_float(uB.x << 16);
            accB[1] += wB * __uint_as_float(uB.x & 0xffff0000u);
            accB[2] += wB * __uint_as_float(uB.y << 16);
            accB[3] += wB * __uint_as_float(uB.y & 0xffff0000u);
            accB[4] += wB * __uint_as_float(uB.z << 16);
            accB[5] += wB * __uint_as_float(uB.z & 0xffff0000u);
            accB[6] += wB * __uint_as_float(uB.w << 16);
            accB[7] += wB * __uint_as_float(uB.w & 0xffff0000u);
        }

#pragma unroll
        for (int i = 0; i < 8; ++i) {
            accA[i] += __shfl_xor(accA[i], 16);
            accA[i] += __shfl_xor(accA[i], 32);
            accB[i] += __shfl_xor(accB[i], 16);
            accB[i] += __shfl_xor(accB[i], 32);
        }
        wsA += __shfl_xor(wsA, 16); wsA += __shfl_xor(wsA, 32);
        wsB += __shfl_xor(wsB, 16); wsB += __shfl_xor(wsB, 32);
        const float scA = (degA > 0) ? 1.0f / wsA : 0.0f;
        const float scB = (degB > 0) ? 1.0f / wsB : 0.0f;

        if (g == 0) {
            const int nodeA = t0 + ltA;
            const int nodeB = t0 + ltB;
            if (nodeA < M) {
                float* dst = out + (size_t)nodeA * UNITS + c * 8;
                *(float4*)dst       = make_float4(accA[0] * scA, accA[1] * scA,
                                                  accA[2] * scA, accA[3] * scA);
                *(float4*)(dst + 4) = make_float4(accA[4] * scA, accA[5] * scA,
                                                  accA[6] * scA, accA[7] * scA);
            }
            if (nodeB < M) {
                float* dst = out + (size_t)nodeB * UNITS + c * 8;
                *(float4*)dst       = make_float4(accB[0] * scB, accB[1] * scB,
                                                  accB[2] * scB, accB[3] * scB);
                *(float4*)(dst + 4) = make_float4(accB[4] * scB, accB[5] * scB,
                                                  accB[6] * scB, accB[7] * scB);
            }
        }
    }
}

// ---------------------------------------------------------------------------
extern "C" void kernel_launch(void* const* d_in, const int* in_sizes, int n_in,
                              void* d_out, int out_size, void* d_ws, size_t ws_size,
                              hipStream_t stream) {
    const float* node_states = (const float*)d_in[0];
    const int*   edges       = (const int*)d_in[1];   // int32 pairs (tgt,src)
    const float* W           = (const float*)d_in[2];
    const float* ka          = (const float*)d_in[3];
    float*       out         = (float*)d_out;

    const int M = N_NODES, E = N_EDGES;

    // workspace layout
    ushort_t* hb     = (ushort_t*)d_ws;                  // M*128 bf16 = 12.8 MB
    float*    a_tgt  = (float*)(hb + (size_t)M * UNITS); // M floats
    float*    a_src  = a_tgt + M;                        // M floats
    int*      gbin   = (int*)(a_src + M);                // 1024*GPAD ints = 64 KB
    int2*     binbuf = (int2*)(gbin + 1024 * GPAD);      // NBINS*BIN_CAP int2 = 8.0 MB
    ushort_t* wt     = (ushort_t*)(binbuf + (size_t)NBINS * BIN_CAP); // 64 KB

    const int nblkB = (E + CHUNK - 1) / CHUNK;           // 196

    prep_wt_zero    <<<(UNITS * IN_FEAT + 255) / 256, 256, 0, stream>>>(W, wt, gbin);
    gemm_mfma       <<<(M + 63) / 64, 256, 0, stream>>>(node_states, wt, ka, hb,
                                                        a_tgt, a_src, M);
    bin_edges       <<<nblkB, 1024, 0, stream>>>(edges, gbin, binbuf, E);
    scatter_aggregate<<<NBINS, 512, 0, stream>>>(binbuf, gbin, a_tgt, a_src,
                                                 hb, out, M);
}